// Round 1
// baseline (453.981 us; speedup 1.0000x reference)
//
#include <hip/hip_runtime.h>
#include <math.h>

#define BB 512
#define TT 49
#define SS 200
#define DD 512
#define KK 128

// ---------------------------------------------------------------------------
// Kernel 1: tfeature[b,d] = mean over s of tfh[b,s,d]
// ---------------------------------------------------------------------------
__global__ void mean_kernel(const float* __restrict__ tfh, float* __restrict__ tfeat) {
    int b = blockIdx.x;
    const float* p = tfh + (size_t)b * SS * DD;
    for (int d = threadIdx.x; d < DD; d += blockDim.x) {
        float acc = 0.f;
        for (int s = 0; s < SS; ++s) acc += p[s * DD + d];
        tfeat[b * DD + d] = acc * (1.0f / SS);
    }
}

// ---------------------------------------------------------------------------
// Kernel 2/5: c[b] = sum_k tanh(vec[b,:] @ W[:,k]) * wp[wp_off + k]
// blockDim = 128 (one thread per k)
// ---------------------------------------------------------------------------
__global__ void cterm_kernel(const float* __restrict__ vecs,   // [B,D]
                             const float* __restrict__ W,      // [D,K]
                             const float* __restrict__ wp,     // [2K]
                             int wp_off,
                             float* __restrict__ cout) {       // [B]
    int b = blockIdx.x;
    __shared__ float v[DD];
    __shared__ float partial[2];
    for (int d = threadIdx.x; d < DD; d += blockDim.x) v[d] = vecs[b * DD + d];
    __syncthreads();
    int k = threadIdx.x;
    float acc = 0.f;
    for (int d = 0; d < DD; ++d) acc += v[d] * W[d * KK + k];
    float val = tanhf(acc) * wp[wp_off + k];
    #pragma unroll
    for (int off = 32; off > 0; off >>= 1) val += __shfl_down(val, off, 64);
    if ((threadIdx.x & 63) == 0) partial[threadIdx.x >> 6] = val;
    __syncthreads();
    if (threadIdx.x == 0) cout[b] = partial[0] + partial[1];
}

// ---------------------------------------------------------------------------
// Kernel 3/6: logits[b,m] = sum_k tanh(A[b,m,:] @ W[:,k]) * wpk[k]
//                           + cterm[b] + bias[m]
// Tiled GEMM: 32 rows x 128 k per block, D reduced in 32-wide LDS tiles.
// 256 threads: thread -> (sg=tid>>5 owns rows sg*4..+3, kg=tid&31 owns k kg*4..+3)
// ---------------------------------------------------------------------------
__global__ void logits_kernel(const float* __restrict__ A,     // [B,M,D]
                              const float* __restrict__ W,     // [D,K]
                              const float* __restrict__ wpk,   // [K] (pre-offset)
                              const float* __restrict__ bias,  // [M]
                              const float* __restrict__ cterm, // [B]
                              float* __restrict__ out,         // [B,M]
                              int M) {
    int b = blockIdx.x;
    int m0 = blockIdx.y * 32;
    int rows = M - m0; if (rows > 32) rows = 32;

    __shared__ float As[32][32];   // transposed: As[d][row]
    __shared__ float Bs[32][KK];   // Bs[d][k]
    __shared__ float red[32][32];  // red[row][kg]

    int tid = threadIdx.x;
    int sg = tid >> 5;    // 0..7
    int kg = tid & 31;    // 0..31

    float acc[4][4];
    #pragma unroll
    for (int i = 0; i < 4; ++i)
        #pragma unroll
        for (int j = 0; j < 4; ++j) acc[i][j] = 0.f;

    const float* Ab = A + (size_t)b * M * DD;

    for (int d0 = 0; d0 < DD; d0 += 32) {
        // load A tile, transposed into LDS
        {
            int r  = tid >> 3;        // 0..31
            int c4 = (tid & 7) * 4;   // 0..28
            float4 v = make_float4(0.f, 0.f, 0.f, 0.f);
            if (r < rows) v = *(const float4*)(Ab + (size_t)(m0 + r) * DD + d0 + c4);
            As[c4 + 0][r] = v.x; As[c4 + 1][r] = v.y;
            As[c4 + 2][r] = v.z; As[c4 + 3][r] = v.w;
        }
        // load B tile [32 d][128 k]
        #pragma unroll
        for (int jj = 0; jj < 4; ++jj) {
            int f  = tid + 256 * jj;   // float4 index, 0..1023
            int r  = f >> 5;
            int c4 = (f & 31) * 4;
            *(float4*)&Bs[r][c4] = *(const float4*)(W + (size_t)(d0 + r) * KK + c4);
        }
        __syncthreads();
        #pragma unroll
        for (int d = 0; d < 32; ++d) {
            float4 a  = *(const float4*)&As[d][sg * 4];
            float4 bb = *(const float4*)&Bs[d][kg * 4];
            float av[4] = {a.x, a.y, a.z, a.w};
            float bv[4] = {bb.x, bb.y, bb.z, bb.w};
            #pragma unroll
            for (int i = 0; i < 4; ++i)
                #pragma unroll
                for (int j = 0; j < 4; ++j) acc[i][j] += av[i] * bv[j];
        }
        __syncthreads();
    }

    // tanh + weighted partial reduce over this thread's 4 k values
    #pragma unroll
    for (int i = 0; i < 4; ++i) {
        float s = 0.f;
        #pragma unroll
        for (int j = 0; j < 4; ++j) s += tanhf(acc[i][j]) * wpk[kg * 4 + j];
        red[sg * 4 + i][kg] = s;
    }
    __syncthreads();
    if (tid < 32 && tid < rows) {
        float s = 0.f;
        #pragma unroll
        for (int j = 0; j < 32; ++j) s += red[tid][j];
        out[(size_t)b * M + m0 + tid] = s + cterm[b] + bias[m0 + tid];
    }
}

// ---------------------------------------------------------------------------
// Kernel 4: Pi = softmax(logits0[b,:]); Vi[b,d] = sum_t Pi[t] * ifeat[b,t,d]
// ---------------------------------------------------------------------------
__global__ void attend0_kernel(const float* __restrict__ logits0,
                               const float* __restrict__ ifeat,
                               float* __restrict__ Vi) {
    int b = blockIdx.x;
    __shared__ float Pi[TT];
    int tid = threadIdx.x;
    if (tid < 64) {
        float v = (tid < TT) ? logits0[b * TT + tid] : -INFINITY;
        float m = v;
        #pragma unroll
        for (int off = 32; off > 0; off >>= 1) m = fmaxf(m, __shfl_xor(m, off, 64));
        float e = (tid < TT) ? expf(v - m) : 0.f;
        float ssum = e;
        #pragma unroll
        for (int off = 32; off > 0; off >>= 1) ssum += __shfl_xor(ssum, off, 64);
        if (tid < TT) Pi[tid] = e / ssum;
    }
    __syncthreads();
    const float* p = ifeat + (size_t)b * TT * DD;
    for (int d = tid; d < DD; d += blockDim.x) {
        float acc = 0.f;
        for (int t = 0; t < TT; ++t) acc += Pi[t] * p[t * DD + d];
        Vi[b * DD + d] = acc;
    }
}

// ---------------------------------------------------------------------------
// Kernel 7: Pt = softmax(logits1[b,:]); out[b,s,d] = Pt[s] * tfh[b,s,d]
// ---------------------------------------------------------------------------
__global__ void attend1_out_kernel(const float* __restrict__ logits1,
                                   const float* __restrict__ tfh,
                                   float* __restrict__ out) {
    int b = blockIdx.x;
    __shared__ float Pt[SS];
    __shared__ float wpart[4];
    int tid = threadIdx.x;
    float v = (tid < SS) ? logits1[(size_t)b * SS + tid] : -INFINITY;
    float m = v;
    #pragma unroll
    for (int off = 32; off > 0; off >>= 1) m = fmaxf(m, __shfl_xor(m, off, 64));
    if ((tid & 63) == 0) wpart[tid >> 6] = m;
    __syncthreads();
    m = fmaxf(fmaxf(wpart[0], wpart[1]), fmaxf(wpart[2], wpart[3]));
    float e = (tid < SS) ? expf(v - m) : 0.f;
    float ssum = e;
    #pragma unroll
    for (int off = 32; off > 0; off >>= 1) ssum += __shfl_xor(ssum, off, 64);
    __syncthreads();
    if ((tid & 63) == 0) wpart[tid >> 6] = ssum;
    __syncthreads();
    ssum = wpart[0] + wpart[1] + wpart[2] + wpart[3];
    if (tid < SS) Pt[tid] = e / ssum;
    __syncthreads();

    const float4* src = (const float4*)(tfh + (size_t)b * SS * DD);
    float4*       dst = (float4*)(out + (size_t)b * SS * DD);
    const int n4 = SS * DD / 4;   // 25600
    for (int idx = tid; idx < n4; idx += blockDim.x) {
        int s = idx >> 7;         // 128 float4 per row
        float p = Pt[s];
        float4 x = src[idx];
        x.x *= p; x.y *= p; x.z *= p; x.w *= p;
        dst[idx] = x;
    }
}

// ---------------------------------------------------------------------------
extern "C" void kernel_launch(void* const* d_in, const int* in_sizes, int n_in,
                              void* d_out, int out_size, void* d_ws, size_t ws_size,
                              hipStream_t stream) {
    const float* ifeature = (const float*)d_in[0];
    const float* tfh      = (const float*)d_in[1];
    const float* wVi0     = (const float*)d_in[2];
    const float* wVt0     = (const float*)d_in[3];
    const float* wp0      = (const float*)d_in[4];
    const float* bias0    = (const float*)d_in[5];
    const float* wVi1     = (const float*)d_in[6];
    const float* wVt1     = (const float*)d_in[7];
    const float* wp1      = (const float*)d_in[8];
    const float* bias1    = (const float*)d_in[9];
    float* out = (float*)d_out;
    float* ws  = (float*)d_ws;

    // ws layout (floats): tfeat[B*D] | Vi[B*D] | c0[B] | c1[B] | l0[B*T] | l1[B*S]
    float* tfeat = ws;
    float* Vi    = ws + BB * DD;
    float* c0    = ws + 2 * BB * DD;
    float* c1    = c0 + BB;
    float* l0    = c1 + BB;
    float* l1    = l0 + BB * TT;

    mean_kernel<<<BB, 256, 0, stream>>>(tfh, tfeat);
    // c0 uses wp0[K + k]  (tanh of broadcast text half of concat)
    cterm_kernel<<<BB, 128, 0, stream>>>(tfeat, wVt0, wp0, KK, c0);
    // logits0: image half of concat -> wp0[0..K)
    logits_kernel<<<dim3(BB, (TT + 31) / 32), 256, 0, stream>>>(
        ifeature, wVi0, wp0, bias0, c0, l0, TT);
    attend0_kernel<<<BB, 256, 0, stream>>>(l0, ifeature, Vi);
    // c1 uses wp1[0..K) (broadcast image half of concat)
    cterm_kernel<<<BB, 128, 0, stream>>>(Vi, wVi1, wp1, 0, c1);
    // logits1: text half of concat -> wp1[K..2K)
    logits_kernel<<<dim3(BB, (SS + 31) / 32), 256, 0, stream>>>(
        tfh, wVt1, wp1 + KK, bias1, c1, l1, SS);
    attend1_out_kernel<<<BB, 256, 0, stream>>>(l1, tfh, out);
}

// Round 2
// 141.035 us; speedup vs baseline: 3.2189x; 3.2189x over previous
//
#include <hip/hip_runtime.h>
#include <math.h>

#define BB 512
#define SS 200
#define DD 512
#define KK 128
#define RR (BB * SS)   // 102400 rows

typedef __attribute__((ext_vector_type(8))) short bf16x8;
typedef __attribute__((ext_vector_type(4))) float f32x4;

__device__ inline unsigned short f2bf(float f) {
    union { float f; unsigned int u; } v; v.f = f;
    unsigned int r = v.u + 0x7FFFu + ((v.u >> 16) & 1u);   // RNE
    return (unsigned short)(r >> 16);
}

// ---------------------------------------------------------------------------
// Wt[col][d] = bf16(W[d][col])  — 128x512 bf16, done once, L2-resident after
// ---------------------------------------------------------------------------
__global__ void wt_kernel(const float* __restrict__ W, unsigned short* __restrict__ Wt) {
    int i = blockIdx.x * 256 + threadIdx.x;   // over 128*512
    int col = i >> 9, d = i & 511;
    Wt[i] = f2bf(W[d * KK + col]);
}

// ---------------------------------------------------------------------------
// logits[row] = sum_k tanh( A[row,:] . Wt[k,:] ) * wpk[k] + bias[row % SS]
// A = tfh flattened [RR, DD] fp32 (converted to bf16 inline).
// Block: 256 threads (4 waves), 128 rows. Wave w owns rows w*32..w*32+31.
// MFMA 16x16x32 bf16, fp32 accum. LDS tiles padded to stride 40 (2-way free).
// ---------------------------------------------------------------------------
__global__ __launch_bounds__(256, 2) void logits_mfma_kernel(
    const float* __restrict__ A,
    const unsigned short* __restrict__ Wt,   // [KK][DD] bf16
    const float* __restrict__ wpk,           // [KK]
    const float* __restrict__ bias,          // [SS]
    float* __restrict__ out)                 // [RR]
{
    __shared__ unsigned short As[128][40];
    __shared__ unsigned short Bs[128][40];

    int tid = threadIdx.x;
    int w = tid >> 6;
    int l = tid & 63;
    int l15 = l & 15;
    int g = l >> 4;
    size_t row0 = (size_t)blockIdx.x * 128;

    f32x4 acc[2][8];
    #pragma unroll
    for (int m = 0; m < 2; ++m)
        #pragma unroll
        for (int n = 0; n < 8; ++n) acc[m][n] = (f32x4){0.f, 0.f, 0.f, 0.f};

    float wv[8];
    #pragma unroll
    for (int n = 0; n < 8; ++n) wv[n] = wpk[n * 16 + l15];

    // staging coords
    int ar = tid >> 1;             // 0..127 (row within tile)
    int ac = (tid & 1) * 16;       // 0 or 16 (col within 32-wide d tile)
    int bc = tid >> 1;             // 0..127 (k col of Wt)
    int bh = (tid & 1) * 16;       // 0 or 16

    for (int d0 = 0; d0 < DD; d0 += 32) {
        // --- stage A: 128 rows x 32 d, fp32 -> bf16 ---
        {
            const float* src = A + (row0 + ar) * DD + d0 + ac;
            float4 v0 = *(const float4*)(src);
            float4 v1 = *(const float4*)(src + 4);
            float4 v2 = *(const float4*)(src + 8);
            float4 v3 = *(const float4*)(src + 12);
            bf16x8 p0, p1;
            p0[0] = (short)f2bf(v0.x); p0[1] = (short)f2bf(v0.y);
            p0[2] = (short)f2bf(v0.z); p0[3] = (short)f2bf(v0.w);
            p0[4] = (short)f2bf(v1.x); p0[5] = (short)f2bf(v1.y);
            p0[6] = (short)f2bf(v1.z); p0[7] = (short)f2bf(v1.w);
            p1[0] = (short)f2bf(v2.x); p1[1] = (short)f2bf(v2.y);
            p1[2] = (short)f2bf(v2.z); p1[3] = (short)f2bf(v2.w);
            p1[4] = (short)f2bf(v3.x); p1[5] = (short)f2bf(v3.y);
            p1[6] = (short)f2bf(v3.z); p1[7] = (short)f2bf(v3.w);
            *(bf16x8*)&As[ar][ac]     = p0;
            *(bf16x8*)&As[ar][ac + 8] = p1;
        }
        // --- stage B: 128 k x 32 d of Wt (already bf16) ---
        {
            const unsigned short* src = Wt + (size_t)bc * DD + d0 + bh;
            bf16x8 q0 = *(const bf16x8*)(src);
            bf16x8 q1 = *(const bf16x8*)(src + 8);
            *(bf16x8*)&Bs[bc][bh]     = q0;
            *(bf16x8*)&Bs[bc][bh + 8] = q1;
        }
        __syncthreads();
        // --- MFMA: wave w rows w*32..+31, all 128 k cols ---
        bf16x8 afrag[2];
        #pragma unroll
        for (int m = 0; m < 2; ++m)
            afrag[m] = *(const bf16x8*)&As[w * 32 + m * 16 + l15][g * 8];
        #pragma unroll
        for (int n = 0; n < 8; ++n) {
            bf16x8 bfrag = *(const bf16x8*)&Bs[n * 16 + l15][g * 8];
            acc[0][n] = __builtin_amdgcn_mfma_f32_16x16x32_bf16(afrag[0], bfrag, acc[0][n], 0, 0, 0);
            acc[1][n] = __builtin_amdgcn_mfma_f32_16x16x32_bf16(afrag[1], bfrag, acc[1][n], 0, 0, 0);
        }
        __syncthreads();
    }

    // --- epilogue: tanh, weight by wpk, reduce over k (cols) ---
    // C/D layout: col = l&15, row = (l>>4)*4 + r   [measured m89]
    float rs[2][4];
    #pragma unroll
    for (int m = 0; m < 2; ++m)
        #pragma unroll
        for (int r = 0; r < 4; ++r) rs[m][r] = 0.f;
    #pragma unroll
    for (int m = 0; m < 2; ++m)
        #pragma unroll
        for (int n = 0; n < 8; ++n)
            #pragma unroll
            for (int r = 0; r < 4; ++r)
                rs[m][r] += tanhf(acc[m][n][r]) * wv[n];

    #pragma unroll
    for (int m = 0; m < 2; ++m)
        #pragma unroll
        for (int r = 0; r < 4; ++r) {
            float v = rs[m][r];
            v += __shfl_xor(v, 1, 64);
            v += __shfl_xor(v, 2, 64);
            v += __shfl_xor(v, 4, 64);
            v += __shfl_xor(v, 8, 64);
            rs[m][r] = v;
        }
    if (l15 == 0) {
        #pragma unroll
        for (int m = 0; m < 2; ++m)
            #pragma unroll
            for (int r = 0; r < 4; ++r) {
                int grow = (int)row0 + w * 32 + m * 16 + g * 4 + r;
                out[grow] = rs[m][r] + bias[grow % SS];
            }
    }
}

// ---------------------------------------------------------------------------
// Pt = softmax(logits[b,:]); out[b,s,:] = Pt[s] * tfh[b,s,:]
// ---------------------------------------------------------------------------
__global__ __launch_bounds__(1024) void softmax_mul_kernel(
    const float* __restrict__ logits,
    const float* __restrict__ tfh,
    float* __restrict__ out)
{
    int b = blockIdx.x;
    int tid = threadIdx.x;
    __shared__ float Pt[SS];
    __shared__ float wpart[16];

    float v = (tid < SS) ? logits[(size_t)b * SS + tid] : -INFINITY;
    float m = v;
    #pragma unroll
    for (int off = 32; off > 0; off >>= 1) m = fmaxf(m, __shfl_xor(m, off, 64));
    if ((tid & 63) == 0) wpart[tid >> 6] = m;
    __syncthreads();
    m = -INFINITY;
    #pragma unroll
    for (int i = 0; i < 16; ++i) m = fmaxf(m, wpart[i]);
    float e = (tid < SS) ? expf(v - m) : 0.f;
    float ssum = e;
    #pragma unroll
    for (int off = 32; off > 0; off >>= 1) ssum += __shfl_xor(ssum, off, 64);
    __syncthreads();   // everyone done reading wpart (max) before overwrite
    if ((tid & 63) == 0) wpart[tid >> 6] = ssum;
    __syncthreads();
    ssum = 0.f;
    #pragma unroll
    for (int i = 0; i < 16; ++i) ssum += wpart[i];
    if (tid < SS) Pt[tid] = e / ssum;
    __syncthreads();

    const float4* src = (const float4*)(tfh + (size_t)b * SS * DD);
    float4*       dst = (float4*)(out + (size_t)b * SS * DD);
    const int n4 = SS * DD / 4;   // 25600, 128 float4 per row
    for (int i = tid; i < n4; i += 1024) {
        float p = Pt[i >> 7];
        float4 x = src[i];
        x.x *= p; x.y *= p; x.z *= p; x.w *= p;
        dst[i] = x;
    }
}

// ---------------------------------------------------------------------------
extern "C" void kernel_launch(void* const* d_in, const int* in_sizes, int n_in,
                              void* d_out, int out_size, void* d_ws, size_t ws_size,
                              hipStream_t stream) {
    const float* tfh   = (const float*)d_in[1];
    const float* wVt1  = (const float*)d_in[7];
    const float* wp1   = (const float*)d_in[8];
    const float* bias1 = (const float*)d_in[9];
    float* out = (float*)d_out;

    // ws layout: Wt bf16 [128*512] (128KB) | logits f32 [RR] (400KB)
    unsigned short* Wt = (unsigned short*)d_ws;
    float* logits = (float*)((char*)d_ws + KK * DD * sizeof(unsigned short));

    wt_kernel<<<KK * DD / 256, 256, 0, stream>>>(wVt1, Wt);
    logits_mfma_kernel<<<RR / 128, 256, 0, stream>>>(tfh, Wt, wp1 + KK, bias1, logits);
    softmax_mul_kernel<<<BB, 1024, 0, stream>>>(logits, tfh, out);
}